// Round 7
// baseline (924.020 us; speedup 1.0000x reference)
//
#include <hip/hip_runtime.h>

#define NN 100000
#define HH 512
#define GG 512
#define NPACK 1280
#define NSTRIP 40
#define XTROWS (NN + 128)      // pad rows so tail-block xt stores are unguarded

typedef unsigned short u16;
typedef unsigned int u32;
typedef __bf16 bf16x8 __attribute__((ext_vector_type(8)));
typedef unsigned short u16x8 __attribute__((ext_vector_type(8)));
typedef float f32x4 __attribute__((ext_vector_type(4)));

__device__ __forceinline__ u16 f2bf(float f) {
    unsigned u = __float_as_uint(f);
    unsigned r = u + 0x7FFFu + ((u >> 16) & 1u);   // RNE
    return (u16)(r >> 16);
}
__device__ __forceinline__ float bf2f(u16 b) {
    return __uint_as_float(((unsigned)b) << 16);
}

// ---------------- prep: tiled transpose into PLAIN W^T bf16 --------------------
// packed col n: [0,256)=ga_g_w1 ; [256,768)=ga_n_w ; [768,1280)=g_w1
// WT[n][k] row-major: byte = n*1024 + k*2. (No swizzle: k_gemm reads B direct
// from L2 into regs — no LDS banks involved.) Blocks 0..159: 64n x 64k tile,
// coalesced float4 reads, LDS transpose, 16-B writes. Block 160: bwv + starts.
__global__ __launch_bounds__(256)
void k_prep(const float* __restrict__ gw1, const float* __restrict__ gb1,
            const float* __restrict__ gw2v,
            const float* __restrict__ nw, const float* __restrict__ nbias,
            const float* __restrict__ aw1, const float* __restrict__ ab1,
            const float* __restrict__ aw2, const int* __restrict__ batch,
            u16* __restrict__ WT, float2* __restrict__ bwv,
            int* __restrict__ starts) {
    __shared__ u16 lt[64][80];           // [n_local][k_local], row stride 160 B
    const int b = blockIdx.x, tid = threadIdx.x;
    if (b < 160) {
        const int bn = b >> 3, bk = b & 7;
        const int N0 = bn * 64, K0 = bk * 64;
        const float* src; int LD, nb0;
        if (N0 < 256)      { src = gw1; LD = 256; nb0 = N0; }
        else if (N0 < 768) { src = nw;  LD = 512; nb0 = N0 - 256; }
        else               { src = aw1; LD = 512; nb0 = N0 - 768; }
        const int kr = tid >> 2, q = tid & 3;            // row K0+kr, n-quarter q
        const float* sp = src + (size_t)(K0 + kr) * LD + nb0 + q * 16;
#pragma unroll
        for (int jj = 0; jj < 4; ++jj) {
            float4 f = *(const float4*)(sp + jj * 4);
            lt[q * 16 + jj * 4 + 0][kr] = f2bf(f.x);
            lt[q * 16 + jj * 4 + 1][kr] = f2bf(f.y);
            lt[q * 16 + jj * 4 + 2][kr] = f2bf(f.z);
            lt[q * 16 + jj * 4 + 3][kr] = f2bf(f.w);
        }
        __syncthreads();
        const int nlcl = tid >> 2, c2 = tid & 3;
        const int n = N0 + nlcl;
#pragma unroll
        for (int cc = 0; cc < 2; ++cc) {
            int c = c2 * 2 + cc;                          // 16-B chunk (8 k-elems)
            size_t byte = (size_t)n * 1024 + (size_t)(K0 / 8 + c) * 16;
            *(u16x8*)((char*)WT + byte) = *(const u16x8*)(&lt[nlcl][c * 8]);
        }
    } else {
        for (int n = tid; n < NPACK; n += 256) {
            float bi, wv;
            if (n < 256)      { bi = gb1[n];        wv = gw2v[n]; }
            else if (n < 768) { bi = nbias[n - 256]; wv = 0.f; }
            else {
                bi = ab1[n - 768];
                float s = 0.f;
                for (int h = 0; h < 8; ++h) s += aw2[(n - 768) * 8 + h];
                wv = s * 0.125f;
            }
            bwv[n] = make_float2(bi, wv);
        }
        for (int g = tid; g <= GG; g += 256) {
            if (g == GG) { starts[GG] = NN; continue; }
            int lo = 0, hi = NN;
            while (lo < hi) { int mid = (lo + hi) >> 1; if (batch[mid] < g) lo = mid + 1; else hi = mid; }
            starts[g] = lo;
        }
    }
}

// ------------- fused GEMM: B direct from L2, NO LDS, NO barriers ---------------
// block = 128 rows as 4 waves x 32 rows (a_reg 128 VGPR, A read once from HBM).
// B (1.31 MB) is L2/L1-resident; each wave streams b-fragments straight into
// regs -- VMEM pipe instead of the contended LDS pipe, zero sync coupling.
// Compiler deep-pipelines the 32 independent 16-B loads per strip (counted
// vmcnt is its strength). Frag addressing: col n's K-row is WT+n*512 elems;
// lane (l16,kq) reads 16 B at elem (nt*32+{0,16}+l16)*512 + kt*32 + kq*8.
// nt 0-7: gate | 8-23: xt ushort2 stores | 24-39: att score.
__global__ __launch_bounds__(256, 2)
void k_gemm(const float* __restrict__ X, const u16* __restrict__ B,
            const float2* __restrict__ bwv,
            const float* __restrict__ gb2, const float* __restrict__ ab2,
            u16* __restrict__ xt, float* __restrict__ gs, float* __restrict__ as_) {
    const int tid = threadIdx.x;
    const int lane = tid & 63;
    const int w = tid >> 6;                  // wave -> rows [w*32, w*32+32)
    const int m0 = blockIdx.x * 128;
    const int l16 = lane & 15, kq = lane >> 4;

    float b2 = gb2[0];
    float bb = 0.f;
#pragma unroll
    for (int h = 0; h < 8; ++h) bb += ab2[h];
    bb *= 0.125f;

    // ---- A panel: 32 rows/wave, fp32 -> bf16 fragments in registers (128 VGPR) ----
    bf16x8 a_reg[2][16];
#pragma unroll
    for (int i = 0; i < 2; ++i) {
        int row = m0 + w * 32 + i * 16 + l16;
        if (row >= NN) row = NN - 1;
        const float* xp = X + (size_t)row * 512 + kq * 8;
#pragma unroll
        for (int kt = 0; kt < 16; ++kt) {
            float4 f0 = *(const float4*)(xp + kt * 32);
            float4 f1 = *(const float4*)(xp + kt * 32 + 4);
            u16x8 u;
            u[0] = f2bf(f0.x); u[1] = f2bf(f0.y); u[2] = f2bf(f0.z); u[3] = f2bf(f0.w);
            u[4] = f2bf(f1.x); u[5] = f2bf(f1.y); u[6] = f2bf(f1.z); u[7] = f2bf(f1.w);
            a_reg[i][kt] = __builtin_bit_cast(bf16x8, u);
        }
    }

    float s_[2][4];              // gate accumulator (nt<8) then att accumulator (nt>=24)
#pragma unroll
    for (int i = 0; i < 2; ++i)
#pragma unroll
        for (int r = 0; r < 4; ++r) s_[i][r] = 0.f;

    // per-lane B base: col (nt*32 + l16), k-chunk kq
    const u16* bp = B + (size_t)l16 * 512 + kq * 8;

    for (int nt = 0; nt < NSTRIP; ++nt) {
        const u16* bp0 = bp + (size_t)nt * 32 * 512;        // cols nt*32 + l16
        const u16* bp1 = bp0 + 16 * 512;                    // cols nt*32 + 16 + l16

        f32x4 acc[2][2];
#pragma unroll
        for (int i = 0; i < 2; ++i) { acc[i][0] = {0.f,0.f,0.f,0.f}; acc[i][1] = {0.f,0.f,0.f,0.f}; }

#pragma unroll
        for (int kt = 0; kt < 16; ++kt) {
            bf16x8 b0 = *(const bf16x8*)(bp0 + kt * 32);    // elem kt*32 + kq*8 (kq in bp)
            bf16x8 b1 = *(const bf16x8*)(bp1 + kt * 32);
#pragma unroll
            for (int i = 0; i < 2; ++i) {
                acc[i][0] = __builtin_amdgcn_mfma_f32_16x16x32_bf16(a_reg[i][kt], b0, acc[i][0], 0, 0, 0);
                acc[i][1] = __builtin_amdgcn_mfma_f32_16x16x32_bf16(a_reg[i][kt], b1, acc[i][1], 0, 0, 0);
            }
        }

        // ---- epilogue. C/D: col = lane&15, row = kq*4 + reg [m89] ----
        float2 bw0 = bwv[nt * 32 + l16];
        float2 bw1 = bwv[nt * 32 + 16 + l16];
        if (nt >= 8 && nt < 24) {
            const int sx = nt - 8;     // xt position p = sx*32 + l16*2 + j (k_post remaps)
#pragma unroll
            for (int i = 0; i < 2; ++i)
#pragma unroll
                for (int r = 0; r < 4; ++r) {
                    int rg = m0 + w * 32 + i * 16 + kq * 4 + r;   // < XTROWS always
                    ushort2 st;
                    st.x = f2bf(fmaxf(acc[i][0][r] + bw0.x, 0.f));
                    st.y = f2bf(fmaxf(acc[i][1][r] + bw1.x, 0.f));
                    *(ushort2*)(xt + (size_t)rg * 512 + sx * 32 + l16 * 2) = st;
                }
        } else {
#pragma unroll
            for (int i = 0; i < 2; ++i)
#pragma unroll
                for (int r = 0; r < 4; ++r)
                    s_[i][r] += fmaxf(acc[i][0][r] + bw0.x, 0.f) * bw0.y
                              + fmaxf(acc[i][1][r] + bw1.x, 0.f) * bw1.y;
            if (nt == 7) {   // gate scores complete: reduce 16 col-lanes, write, reset
#pragma unroll
                for (int i = 0; i < 2; ++i)
#pragma unroll
                    for (int r = 0; r < 4; ++r) {
                        float pg = s_[i][r];
                        pg += __shfl_xor(pg, 1); pg += __shfl_xor(pg, 2);
                        pg += __shfl_xor(pg, 4); pg += __shfl_xor(pg, 8);
                        int rg = m0 + w * 32 + i * 16 + kq * 4 + r;
                        if (l16 == 0 && rg < NN) gs[rg] = pg + b2;
                        s_[i][r] = 0.f;
                    }
            }
        }
    }

    // ---- att scores: reduce over 16 col-lanes, coalesced write, no atomics ----
#pragma unroll
    for (int i = 0; i < 2; ++i)
#pragma unroll
        for (int r = 0; r < 4; ++r) {
            float pa = s_[i][r];
            pa += __shfl_xor(pa, 1); pa += __shfl_xor(pa, 2);
            pa += __shfl_xor(pa, 4); pa += __shfl_xor(pa, 8);
            int rg = m0 + w * 32 + i * 16 + kq * 4 + r;
            if (l16 == 0 && rg < NN) as_[rg] = pa + bb;
        }
}

// --------- fused post: segment softmax (gate+attn) + weighted embedding -------
// One block per graph. Pass1 max, pass2 expsum, pass3 chunked: gate chunk into
// LDS (+ attn global write), then all threads stream xt rows (8-deep unroll for
// MLP: 32 B/lane in flight). xt position p -> col = (p>>5)*32 + ((p>>1)&15) + (p&1)*16
__global__ __launch_bounds__(256)
void k_post(const float* __restrict__ gs, const float* __restrict__ as_,
            const u16* __restrict__ xt, const int* __restrict__ starts,
            float* __restrict__ out_emb, float* __restrict__ out_att) {
    const int g = blockIdx.x;
    const int s0 = starts[g], s1 = starts[g + 1];
    const int tid = threadIdx.x, lane = tid & 63, w = tid >> 6;
    __shared__ float red[8];
    __shared__ float gbuf[1024];

    float lmg = -3.0e38f, lma = -3.0e38f;
    for (int i = s0 + tid; i < s1; i += 256) {
        lmg = fmaxf(lmg, gs[i]); lma = fmaxf(lma, as_[i]);
    }
    for (int o = 32; o; o >>= 1) {
        lmg = fmaxf(lmg, __shfl_xor(lmg, o));
        lma = fmaxf(lma, __shfl_xor(lma, o));
    }
    if (lane == 0) { red[w] = lmg; red[4 + w] = lma; }
    __syncthreads();
    float Mg = fmaxf(fmaxf(red[0], red[1]), fmaxf(red[2], red[3]));
    float Ma = fmaxf(fmaxf(red[4], red[5]), fmaxf(red[6], red[7]));
    __syncthreads();
    float sgv = 0.f, sav = 0.f;
    for (int i = s0 + tid; i < s1; i += 256) {
        sgv += expf(gs[i] - Mg); sav += expf(as_[i] - Ma);
    }
    for (int o = 32; o; o >>= 1) { sgv += __shfl_xor(sgv, o); sav += __shfl_xor(sav, o); }
    if (lane == 0) { red[w] = sgv; red[4 + w] = sav; }
    __syncthreads();
    const float Dg = red[0] + red[1] + red[2] + red[3] + 1e-16f;
    const float Da = red[4] + red[5] + red[6] + red[7] + 1e-16f;

    const int c2 = tid;
    const int col0 = (c2 >> 4) * 32 + (c2 & 15);
    float a0 = 0.f, a1 = 0.f;
    for (int nb = s0; nb < s1; nb += 1024) {
        const int ce = min(s1, nb + 1024);
        __syncthreads();                     // gbuf free for refill
        for (int i = nb + tid; i < ce; i += 256) {
            gbuf[i - nb] = expf(gs[i] - Mg) / Dg;
            out_att[i]   = expf(as_[i] - Ma) / Da;
        }
        __syncthreads();
        const int cl = ce - nb;
        int j = 0;
        for (; j + 8 <= cl; j += 8) {
            const size_t n = (size_t)(nb + j);
            ushort2 u0 = ((const ushort2*)(xt + (n + 0) * 512))[c2];
            ushort2 u1 = ((const ushort2*)(xt + (n + 1) * 512))[c2];
            ushort2 u2 = ((const ushort2*)(xt + (n + 2) * 512))[c2];
            ushort2 u3 = ((const ushort2*)(xt + (n + 3) * 512))[c2];
            ushort2 u4 = ((const ushort2*)(xt + (n + 4) * 512))[c2];
            ushort2 u5 = ((const ushort2*)(xt + (n + 5) * 512))[c2];
            ushort2 u6 = ((const ushort2*)(xt + (n + 6) * 512))[c2];
            ushort2 u7 = ((const ushort2*)(xt + (n + 7) * 512))[c2];
            float g0 = gbuf[j],     g1 = gbuf[j + 1], g2 = gbuf[j + 2], g3 = gbuf[j + 3];
            float g4 = gbuf[j + 4], g5 = gbuf[j + 5], g6 = gbuf[j + 6], g7 = gbuf[j + 7];
            a0 += g0 * bf2f(u0.x); a1 += g0 * bf2f(u0.y);
            a0 += g1 * bf2f(u1.x); a1 += g1 * bf2f(u1.y);
            a0 += g2 * bf2f(u2.x); a1 += g2 * bf2f(u2.y);
            a0 += g3 * bf2f(u3.x); a1 += g3 * bf2f(u3.y);
            a0 += g4 * bf2f(u4.x); a1 += g4 * bf2f(u4.y);
            a0 += g5 * bf2f(u5.x); a1 += g5 * bf2f(u5.y);
            a0 += g6 * bf2f(u6.x); a1 += g6 * bf2f(u6.y);
            a0 += g7 * bf2f(u7.x); a1 += g7 * bf2f(u7.y);
        }
        for (; j < cl; ++j) {
            ushort2 u = ((const ushort2*)(xt + (size_t)(nb + j) * 512))[c2];
            float gj = gbuf[j];
            a0 += gj * bf2f(u.x); a1 += gj * bf2f(u.y);
        }
    }
    out_emb[g * 512 + col0] = a0;        // every (g,col) written: no pre-zero needed
    out_emb[g * 512 + col0 + 16] = a1;
}

extern "C" void kernel_launch(void* const* d_in, const int* in_sizes, int n_in,
                              void* d_out, int out_size, void* d_ws, size_t ws_size,
                              hipStream_t stream) {
    const float* x       = (const float*)d_in[0];
    const int*   batch   = (const int*)d_in[1];
    const float* ga_g_w1 = (const float*)d_in[2];
    const float* ga_g_b1 = (const float*)d_in[3];
    const float* ga_g_w2 = (const float*)d_in[4];
    const float* ga_g_b2 = (const float*)d_in[5];
    const float* ga_n_w  = (const float*)d_in[6];
    const float* ga_n_b  = (const float*)d_in[7];
    const float* g_w1    = (const float*)d_in[8];
    const float* g_b1    = (const float*)d_in[9];
    const float* g_w2    = (const float*)d_in[10];
    const float* g_b2    = (const float*)d_in[11];

    float* out_emb = (float*)d_out;                  // (512, 512)
    float* out_att = out_emb + GG * HH;              // (100000,)

    char* p = (char*)d_ws;
    size_t off = 0;
    auto alloc = [&](size_t bytes) -> char* {
        char* q = p + off;
        off += (bytes + 255) & ~(size_t)255;
        return q;
    };
    u16*    xt    = (u16*)   alloc((size_t)XTROWS * HH * 2);  // relu(x@ga_n_w+b) bf16 (padded)
    u16*    WT    = (u16*)   alloc((size_t)NPACK * 512 * 2);  // plain W^T bf16 [n][k]
    float2* bwv   = (float2*)alloc(NPACK * 8);                // (bias, wvec) pairs
    float*  gs    = (float*) alloc((size_t)NN * 4);
    float*  as_   = (float*) alloc((size_t)NN * 4);
    int*    starts= (int*)   alloc((GG + 1) * 4);

    k_prep<<<161, 256, 0, stream>>>(ga_g_w1, ga_g_b1, ga_g_w2, ga_n_w, ga_n_b,
                                    g_w1, g_b1, g_w2, batch, WT, bwv, starts);
    k_gemm<<<782, 256, 0, stream>>>(x, WT, bwv, ga_g_b2, g_b2, xt, gs, as_);
    k_post<<<GG, 256, 0, stream>>>(gs, as_, xt, starts, out_emb, out_att);
}